// Round 6
// baseline (523.269 us; speedup 1.0000x reference)
//
#include <hip/hip_runtime.h>
#include <cstddef>
#include <cstdint>

#define T_ 12
#define H_ 64
#define CIN_ 16
#define F_ 768          // H*T
#define BN_EPS 1e-5f
#define RPITCH 88       // sxb row pitch in ushorts (16B-aligned)
#define SLOTS 64        // fixed-stride CSR slots per node

// Plane-major feature layout for intermediates (xabf/xbbf/agg):
// 8 planes; plane s holds flat channels [96s, 96s+96) of every node:
// ushort index = (s*n + node)*96 + (flat%96). Flat semantics unchanged.

typedef float v2f __attribute__((ext_vector_type(2)));
typedef short s8v __attribute__((ext_vector_type(8)));
typedef float f4v __attribute__((ext_vector_type(4)));

__device__ __forceinline__ unsigned short f2bf(float f) {
    unsigned u = __float_as_uint(f);
    unsigned r = (u + 0x7FFFu + ((u >> 16) & 1u)) >> 16;
    return (unsigned short)r;
}
__device__ __forceinline__ float bf2f(unsigned short h) {
    return __uint_as_float(((unsigned)h) << 16);
}
__device__ __forceinline__ v2f bf2x2(unsigned u) {
    v2f r;
    r.x = __uint_as_float(u << 16);
    r.y = __uint_as_float(u & 0xFFFF0000u);
    return r;
}
__device__ __forceinline__ v2f pkfma(v2f a, v2f b, v2f c) {
    return __builtin_elementwise_fma(a, b, c);
}

// ---------------- slot-CSR build ----------------

__global__ void k_init(int* __restrict__ cursor, int n) {
    int i = blockIdx.x * 256 + threadIdx.x;
    if (i < n) cursor[i] = 0;
}

// ---------------- fused: wprep(+wkA pack) | scatter | embed ----------------

__global__ __launch_bounds__(256) void k_fused(
        const float* __restrict__ gcn_W, const float* __restrict__ gcn_b,
        const float* __restrict__ conv_w,
        unsigned short* __restrict__ wkA, float* __restrict__ bkp,
        const int* __restrict__ srcv, const int* __restrict__ dstv,
        int* __restrict__ cursor, int* __restrict__ csr_src, int e,
        const float* __restrict__ x, const float* __restrict__ We,
        const float* __restrict__ be, unsigned short* __restrict__ xbf, int nT,
        int nbE, int n) {
    __shared__ float smem[5312];
    int b = blockIdx.x;
    int tid = threadIdx.x;

    if (b < 36) {
        // ---- wprep: wk[l,k][c][o] = sum_d gcn_W[l][c][d] * conv_w[l][o][d][k]
        int l = b / 12, k = (b / 4) % 3, cq = b & 3;
        const float* Wg = gcn_W + (size_t)l * 4096;
        const float* cw = conv_w + (size_t)l * 12288;
        float* scwT = smem;            // [64][66]
        float* sWg  = smem + 4224;     // [16][64]
        float* sgb  = smem + 5248;     // [64]
        for (int i = tid; i < 4096; i += 256)
            scwT[(i & 63) * 66 + (i >> 6)] = cw[(size_t)i * 3 + k];
        for (int i = tid; i < 1024; i += 256)
            sWg[i] = Wg[cq * 16 * 64 + i];
        if (tid < 64) sgb[tid] = gcn_b[(size_t)l * 64 + tid];
        __syncthreads();
#pragma unroll
        for (int j = 0; j < 4; j++) {
            int idx = j * 256 + tid;
            int cc = idx >> 6;
            int o  = idx & 63;
            float acc = 0.f;
            for (int d = 0; d < 64; d++)
                acc += sWg[cc * 64 + d] * scwT[d * 66 + o];
            int cful = cq * 16 + cc;
            int kidx = k * 64 + cful;
            int ks = kidx >> 5, r = kidx & 31;
            int ln = (r >> 3) * 16 + (o & 15);
            int jj = r & 7;
            wkA[((((size_t)l * 24) + (o >> 4) * 6 + ks) * 64 + ln) * 8 + jj] =
                f2bf(acc);
        }
        if (cq == 0 && tid < 64) {
            int o = tid;
            float acc = 0.f;
            for (int d = 0; d < 64; d++)
                acc += sgb[d] * scwT[d * 66 + o];
            bkp[((size_t)l * 3 + k) * 64 + o] = acc;
        }
        return;
    }
    if (b < 36 + nbE) {
        int i = (b - 36) * 256 + tid;
        if (i < e) {
            int d = dstv[i], s = srcv[i];
            int pos = atomicAdd(&cursor[d], 1);
            if (pos < SLOTS) csr_src[d * SLOTS + pos] = s;
        }
        return;
    }
    // ---- embed (plane-major output) ----
    float* sW = smem;
    float* sb = smem + 1024;
    for (int i = tid; i < CIN_ * H_; i += 256) sW[i] = We[i];
    if (tid < H_) sb[tid] = be[tid];
    __syncthreads();
    int h4  = tid & 15;
    int ntl = tid >> 4;
    int nt  = (b - 36 - nbE) * 16 + ntl;
    if (nt >= nT) return;
    const float4* xp = (const float4*)(x + (size_t)nt * CIN_);
    float4 xv4[4];
    xv4[0] = xp[0]; xv4[1] = xp[1]; xv4[2] = xp[2]; xv4[3] = xp[3];
    const float* xs = (const float*)xv4;
    float acc[4];
#pragma unroll
    for (int j = 0; j < 4; j++) acc[j] = sb[h4 * 4 + j];
#pragma unroll
    for (int c = 0; c < CIN_; c++) {
        float4 w = *(const float4*)&sW[c * H_ + h4 * 4];
        float xc = xs[c];
        acc[0] += xc * w.x; acc[1] += xc * w.y;
        acc[2] += xc * w.z; acc[3] += xc * w.w;
    }
    ushort4 h;
    h.x = f2bf(fmaxf(acc[0], 0.f)); h.y = f2bf(fmaxf(acc[1], 0.f));
    h.z = f2bf(fmaxf(acc[2], 0.f)); h.w = f2bf(fmaxf(acc[3], 0.f));
    int node = nt / 12, tt = nt - node * 12;
    int flat = tt * 64 + h4 * 4;
    int s = flat / 96, rem = flat - s * 96;   // 4-run never crosses plane
    *(ushort4*)&xbf[((size_t)s * n + node) * 96 + rem] = h;
}

// ---------------- post: pack(src*48 uint-units, coef) + dinv ----------------

__global__ __launch_bounds__(256) void k_post(
        const int* __restrict__ cursor, const int* __restrict__ csr_src,
        int2* __restrict__ pack, float* __restrict__ dinv, int n) {
    int i = blockIdx.x * 256 + threadIdx.x;
    int node = i >> 6, slot = i & 63;
    if (node >= n) return;
    int deg = cursor[node];
    float dn = rsqrtf((float)(deg + 1));
    if (slot == 0) dinv[node] = dn;
    if (slot < min(deg, SLOTS)) {
        int s = csr_src[node * SLOTS + slot];
        float cf = rsqrtf((float)(cursor[s] + 1)) * dn;
        pack[node * SLOTS + slot] = make_int2(s * 48, __float_as_int(cf));
    }
}

// ---------------- XCD-sliced gather (plane-major) ----------------
// block b: slice sl = b&7 -> XCD sl; node group b>>3; one wave per node.
// Plane sl is a contiguous n*192B region: per-XCD L2 footprint = 3.84 MB,
// line-aligned, no cross-XCD line sharing. agg stored nontemporal (no L2
// allocate); pack loaded nontemporal (streaming).

__global__ __launch_bounds__(256, 8) void k_gather(
        const unsigned short* __restrict__ xin,
        unsigned short* __restrict__ agg,
        const int* __restrict__ degv, const int2* __restrict__ pack,
        const float* __restrict__ dinv, int n) {
    __shared__ int2 sed[4 * SLOTS];
    int b = blockIdx.x;
    int sl = b & 7;
    int g = b >> 3;
    int wave = threadIdx.x >> 6, lane = threadIdx.x & 63;
    int node = g * 4 + wave;
    if (node >= n) return;
    int cnt = min(degv[node], SLOTS);
    if (lane < cnt) {
        long long v = __builtin_nontemporal_load(
            (const long long*)&pack[node * SLOTS + lane]);
        sed[wave * SLOTS + lane] = *(int2*)&v;
    }
    int planeU = sl * (n * 48);                 // uint units, < 2^31
    const unsigned* xu = (const unsigned*)xin + planeU;
    int lb = (lane < 48 ? lane : 47);
    float dn = dinv[node];
    float cs = dn * dn;
    v2f cs2 = {cs, cs};
    v2f acc = bf2x2(xu[node * 48 + lb]) * cs2;
    const int2* sp = &sed[wave * SLOTS];
    int e = 0;
    for (; e + 3 < cnt; e += 4) {
        int2 p0 = sp[e], p1 = sp[e + 1], p2 = sp[e + 2], p3 = sp[e + 3];
        unsigned u0 = xu[p0.x + lb];
        unsigned u1 = xu[p1.x + lb];
        unsigned u2 = xu[p2.x + lb];
        unsigned u3 = xu[p3.x + lb];
        v2f c0 = {__int_as_float(p0.y), __int_as_float(p0.y)};
        v2f c1 = {__int_as_float(p1.y), __int_as_float(p1.y)};
        v2f c2 = {__int_as_float(p2.y), __int_as_float(p2.y)};
        v2f c3 = {__int_as_float(p3.y), __int_as_float(p3.y)};
        acc = pkfma(bf2x2(u0), c0, acc);
        acc = pkfma(bf2x2(u1), c1, acc);
        acc = pkfma(bf2x2(u2), c2, acc);
        acc = pkfma(bf2x2(u3), c3, acc);
    }
    for (; e < cnt; e++) {
        int2 p0 = sp[e];
        unsigned u0 = xu[p0.x + lb];
        v2f c0 = {__int_as_float(p0.y), __int_as_float(p0.y)};
        acc = pkfma(bf2x2(u0), c0, acc);
    }
    if (lane < 48) {
        unsigned o = (unsigned)f2bf(acc.x) | ((unsigned)f2bf(acc.y) << 16);
        unsigned* au = (unsigned*)agg + planeU;
        __builtin_nontemporal_store(o, &au[node * 48 + lane]);
    }
}

// ---------------- conv core (stage agg -> LDS, MFMA, BN epilogue) ----------
// Staging: lane covers flat ushorts [12*lane, 12*lane+12) of its node's row,
// read from plane (lane>>3) at uint2 offset node*24 + (lane&7)*3 — same
// values, same order as the previous row-major staging.

#define CONV_CORE()                                                            \
    int tid = threadIdx.x;                                                     \
    int n0 = blockIdx.x * 8;                                                   \
    int wave = tid >> 6, lane = tid & 63;                                      \
    for (int i = tid; i < 8 * 2 * RPITCH; i += 256) {                          \
        int s = i / (2 * RPITCH);                                              \
        int r = i - s * (2 * RPITCH);                                          \
        int row = (r < RPITCH) ? 0 : 13;                                       \
        int c = (r < RPITCH) ? r : r - RPITCH;                                 \
        sxb[s * 14 * RPITCH + row * RPITCH + c] = 0;                           \
    }                                                                          \
    {                                                                          \
        const uint2* ab = (const uint2*)agg;                                   \
        int pofs = (lane >> 3) * (n * 24) + (lane & 7) * 3;                    \
        for (int si = 0; si < 2; si++) {                                       \
            int s = wave * 2 + si;                                             \
            int nn = n0 + s; if (nn >= n) nn = n - 1;                          \
            const uint2* ap = ab + pofs + nn * 24;                             \
            uint2 u0 = ap[0], u1 = ap[1], u2 = ap[2];                          \
            unsigned short* wp = &sxb[s * 14 * RPITCH + RPITCH + lane];        \
            wp[0]           = (unsigned short)u0.x;                            \
            wp[RPITCH]      = (unsigned short)(u0.x >> 16);                    \
            wp[2 * RPITCH]  = (unsigned short)u0.y;                            \
            wp[3 * RPITCH]  = (unsigned short)(u0.y >> 16);                    \
            wp[4 * RPITCH]  = (unsigned short)u1.x;                            \
            wp[5 * RPITCH]  = (unsigned short)(u1.x >> 16);                    \
            wp[6 * RPITCH]  = (unsigned short)u1.y;                            \
            wp[7 * RPITCH]  = (unsigned short)(u1.y >> 16);                    \
            wp[8 * RPITCH]  = (unsigned short)u2.x;                            \
            wp[9 * RPITCH]  = (unsigned short)(u2.x >> 16);                    \
            wp[10 * RPITCH] = (unsigned short)u2.y;                            \
            wp[11 * RPITCH] = (unsigned short)(u2.y >> 16);                    \
        }                                                                      \
    }                                                                          \
    __syncthreads();                                                           \
    int mt = wave;                                                             \
    int q = lane >> 4;                                                         \
    int l15 = lane & 15;                                                       \
    s8v afr[6];                                                                \
    const s8v* Ap = (const s8v*)wkA;                                           \
    for (int ks = 0; ks < 6; ks++) afr[ks] = Ap[(mt * 6 + ks) * 64 + lane];    \
    int obase = mt * 16 + q * 4;                                               \
    float scl[4], shf[4], ball[4], bk0a[4], bk2a[4];                           \
    for (int r = 0; r < 4; r++) {                                              \
        int o = obase + r;                                                     \
        float sc = bng[o] * rsqrtf(bnv[o] + BN_EPS);                           \
        scl[r] = sc;                                                           \
        shf[r] = bnb[o] - bnm[o] * sc;                                         \
        float b0 = bkp[o], b1 = bkp[64 + o], b2 = bkp[128 + o];                \
        ball[r] = cb[o] + b0 + b1 + b2;                                        \
        bk0a[r] = b0; bk2a[r] = b2;                                            \
    }                                                                          \
    f4v accv[6];                                                               \
    for (int nt = 0; nt < 6; nt++) {                                           \
        int nidx = nt * 16 + l15;                                              \
        int s = nidx / 12, t = nidx - 12 * s;                                  \
        const s8v* bp = (const s8v*)&sxb[s * 14 * RPITCH + t * RPITCH + q * 8];\
        f4v acc = {0.f, 0.f, 0.f, 0.f};                                        \
        acc = __builtin_amdgcn_mfma_f32_16x16x32_bf16(afr[0], bp[0],  acc, 0, 0, 0); \
        acc = __builtin_amdgcn_mfma_f32_16x16x32_bf16(afr[1], bp[4],  acc, 0, 0, 0); \
        acc = __builtin_amdgcn_mfma_f32_16x16x32_bf16(afr[2], bp[11], acc, 0, 0, 0); \
        acc = __builtin_amdgcn_mfma_f32_16x16x32_bf16(afr[3], bp[15], acc, 0, 0, 0); \
        acc = __builtin_amdgcn_mfma_f32_16x16x32_bf16(afr[4], bp[22], acc, 0, 0, 0); \
        acc = __builtin_amdgcn_mfma_f32_16x16x32_bf16(afr[5], bp[26], acc, 0, 0, 0); \
        accv[nt] = acc;                                                        \
    }                                                                          \
    __syncthreads();                                                           \
    for (int nt = 0; nt < 6; nt++) {                                           \
        int nidx = nt * 16 + l15;                                              \
        int s = nidx / 12, t = nidx - 12 * s;                                  \
        unsigned short* dp = &sxb[s * F_ + t];                                 \
        for (int r = 0; r < 4; r++) {                                          \
            float bias = ball[r];                                              \
            if (t == 0)  bias -= bk0a[r];                                      \
            if (t == 11) bias -= bk2a[r];                                      \
            float v = (accv[nt][r] + bias) * scl[r] + shf[r];                  \
            dp[(obase + r) * 12] = f2bf(v);                                    \
        }                                                                      \
    }                                                                          \
    __syncthreads();

// ---------------- conv layers 0,1: + residual, writes xout (plane-major) ---

__global__ __launch_bounds__(256, 8) void k_conv(
        const unsigned short* __restrict__ agg,
        const unsigned short* __restrict__ xin,
        unsigned short* __restrict__ xout,
        const unsigned short* __restrict__ wkA,
        const float* __restrict__ bkp, const float* __restrict__ cb,
        const float* __restrict__ bng, const float* __restrict__ bnb,
        const float* __restrict__ bnm, const float* __restrict__ bnv,
        int n) {
    __shared__ __align__(16) unsigned short sxb[8 * 14 * RPITCH];
    CONV_CORE()

#pragma unroll
    for (int cidx = 0; cidx < 3; cidx++) {
        int c = cidx * 256 + tid;
        int s = c / 96, off = c - s * 96;
        int nn = n0 + s;
        if (nn >= n) continue;
        int sp = off / 12, rem = off - sp * 12;     // plane, uint4-within
        int gidx = sp * (n * 12) + nn * 12 + rem;   // uint4 units
        uint4 dv = *(const uint4*)&sxb[s * F_ + off * 8];
        uint4 rv = ((const uint4*)xin)[gidx];
        uint4 ov;
        unsigned* dvp = (unsigned*)&dv;
        unsigned* rvp = (unsigned*)&rv;
        unsigned* ovp = (unsigned*)&ov;
#pragma unroll
        for (int w = 0; w < 4; w++) {
            v2f d2 = bf2x2(dvp[w]);
            v2f r2 = bf2x2(rvp[w]);
            float lo = fmaxf(d2.x + r2.x, 0.f);
            float hi = fmaxf(d2.y + r2.y, 0.f);
            ovp[w] = (unsigned)f2bf(lo) | ((unsigned)f2bf(hi) << 16);
        }
        ((uint4*)xout)[gidx] = ov;
    }
}

// ---------------- conv layer 2 fused with dual attention + output MLP ------

__global__ __launch_bounds__(256, 7) void k_conv_attn(
        const unsigned short* __restrict__ agg,
        const unsigned short* __restrict__ xin,
        const unsigned short* __restrict__ wkA,
        const float* __restrict__ bkp, const float* __restrict__ cb,
        const float* __restrict__ bng, const float* __restrict__ bnb,
        const float* __restrict__ bnm, const float* __restrict__ bnv,
        const float* __restrict__ taw1, const float* __restrict__ tab1,
        const float* __restrict__ taw2, const float* __restrict__ tab2,
        const float* __restrict__ faw1, const float* __restrict__ fab1,
        const float* __restrict__ faw2, const float* __restrict__ fab2,
        const float* __restrict__ ow1, const float* __restrict__ ob1,
        const float* __restrict__ ow2, const float* __restrict__ ob2,
        float* __restrict__ out, int n) {
    __shared__ __align__(16) unsigned short sxb[8 * 14 * RPITCH];
    __shared__ float sft[96 + 520];    // s_tw [8][12] + s_xf [8][65]
    CONV_CORE()

    // residual + relu, write back to LDS (no global store)
#pragma unroll
    for (int cidx = 0; cidx < 3; cidx++) {
        int c = cidx * 256 + tid;
        int s = c / 96, off = c - s * 96;
        int nn = n0 + s; if (nn >= n) nn = n - 1;
        int sp = off / 12, rem = off - sp * 12;
        int gidx = sp * (n * 12) + nn * 12 + rem;
        uint4 dv = *(const uint4*)&sxb[s * F_ + off * 8];
        uint4 rv = ((const uint4*)xin)[gidx];
        unsigned* dvp = (unsigned*)&dv;
        unsigned* rvp = (unsigned*)&rv;
#pragma unroll
        for (int w = 0; w < 4; w++) {
            v2f d2 = bf2x2(dvp[w]);
            v2f r2 = bf2x2(rvp[w]);
            float lo = fmaxf(d2.x + r2.x, 0.f);
            float hi = fmaxf(d2.y + r2.y, 0.f);
            dvp[w] = (unsigned)f2bf(lo) | ((unsigned)f2bf(hi) << 16);
        }
        *(uint4*)&sxb[s * F_ + off * 8] = dv;
    }
    __syncthreads();

    float* s_tw = sft;          // [8][12]
    float* s_xf = sft + 96;     // [8][65]

    // ---- temporal-attn MLP: 32 threads/node, thread owns hidden unit m ----
    {
        int s2 = tid >> 5, m = tid & 31;
        float bm = tab1[m];
        v2f aa0 = {bm, bm}, aa1 = aa0, aa2 = aa0;
        v2f aa3 = aa0, aa4 = aa0, aa5 = aa0;
        const unsigned short* xr = &sxb[s2 * F_];
        float tb2 = tab2[0];
        for (int hh = 0; hh < 64; hh++) {
            const uint2* xp2 = (const uint2*)&xr[hh * 12];
            uint2 w0 = xp2[0], w1 = xp2[1], w2 = xp2[2];
            float wv = taw1[hh * 32 + m];
            v2f wv2 = {wv, wv};
            aa0 = pkfma(bf2x2(w0.x), wv2, aa0);
            aa1 = pkfma(bf2x2(w0.y), wv2, aa1);
            aa2 = pkfma(bf2x2(w1.x), wv2, aa2);
            aa3 = pkfma(bf2x2(w1.y), wv2, aa3);
            aa4 = pkfma(bf2x2(w2.x), wv2, aa4);
            aa5 = pkfma(bf2x2(w2.y), wv2, aa5);
        }
        float w2v = taw2[m];
        float av[12] = {aa0.x, aa0.y, aa1.x, aa1.y, aa2.x, aa2.y,
                        aa3.x, aa3.y, aa4.x, aa4.y, aa5.x, aa5.y};
#pragma unroll
        for (int t = 0; t < 12; t++) {
            float p = fmaxf(av[t], 0.f) * w2v;
            p += __shfl_xor(p, 1); p += __shfl_xor(p, 2);
            p += __shfl_xor(p, 4); p += __shfl_xor(p, 8);
            p += __shfl_xor(p, 16);
            if (m == 0) s_tw[s2 * 12 + t] = p + tb2;
        }
    }
    __syncthreads();

    // ---- softmax(tw), xt, feature attention: wave handles 2 nodes ----
    {
        float fb2 = fab2[0];
        for (int qi = 0; qi < 2; qi++) {
            int ss = wave * 2 + qi;
            float tw[12];
#pragma unroll
            for (int t = 0; t < 12; t++) tw[t] = s_tw[ss * 12 + t];
            float mx = tw[0];
#pragma unroll
            for (int t = 1; t < 12; t++) mx = fmaxf(mx, tw[t]);
            float sum = 0.f;
#pragma unroll
            for (int t = 0; t < 12; t++) { tw[t] = __expf(tw[t] - mx); sum += tw[t]; }
            float inv = 1.f / sum;
            const uint2* xp2 = (const uint2*)&sxb[ss * F_ + lane * 12];
            uint2 w0 = xp2[0], w1 = xp2[1], w2 = xp2[2];
            v2f x0 = bf2x2(w0.x), x1 = bf2x2(w0.y), x2 = bf2x2(w1.x);
            v2f x3 = bf2x2(w1.y), x4 = bf2x2(w2.x), x5 = bf2x2(w2.y);
            float xv[12] = {x0.x, x0.y, x1.x, x1.y, x2.x, x2.y,
                            x3.x, x3.y, x4.x, x4.y, x5.x, x5.y};
            float xt[12];
#pragma unroll
            for (int t = 0; t < 12; t++) xt[t] = xv[t] * tw[t] * inv;
            float lf = fb2;
#pragma unroll
            for (int mm = 0; mm < 6; mm++) {
                float v = fab1[mm];
#pragma unroll
                for (int t = 0; t < 12; t++) v += xt[t] * faw1[t * 6 + mm];
                lf += fmaxf(v, 0.f) * faw2[mm];
            }
            float m2v = lf;
#pragma unroll
            for (int off = 32; off >= 1; off >>= 1)
                m2v = fmaxf(m2v, __shfl_xor(m2v, off));
            float ev = __expf(lf - m2v);
            float sev = ev;
#pragma unroll
            for (int off = 32; off >= 1; off >>= 1) sev += __shfl_xor(sev, off);
            float fwv = ev / sev;
            float xs = 0.f;
#pragma unroll
            for (int t = 0; t < 12; t++) xs += xt[t];
            s_xf[ss * 65 + lane] = fwv * xs;
        }
    }
    __syncthreads();

    // ---- output MLP: 32 threads/node ----
    {
        int s2 = tid >> 5, m = tid & 31;
        float v = ob1[m];
        const float* xfp = &s_xf[s2 * 65];
        for (int hh = 0; hh < 64; hh++) v += xfp[hh] * ow1[hh * 32 + m];
        float p = fmaxf(v, 0.f) * ow2[m];
        p += __shfl_xor(p, 1); p += __shfl_xor(p, 2);
        p += __shfl_xor(p, 4); p += __shfl_xor(p, 8);
        p += __shfl_xor(p, 16);
        if (m == 0 && n0 + s2 < n) out[n0 + s2] = p + ob2[0];
    }
}

// ---------------- launcher ----------------

extern "C" void kernel_launch(void* const* d_in, const int* in_sizes, int n_in,
                              void* d_out, int out_size, void* d_ws, size_t ws_size,
                              hipStream_t stream) {
    const float* x      = (const float*)d_in[0];
    const int*   ei     = (const int*)d_in[1];
    const float* We     = (const float*)d_in[2];
    const float* be     = (const float*)d_in[3];
    const float* gcn_W  = (const float*)d_in[4];
    const float* gcn_b  = (const float*)d_in[5];
    const float* conv_w = (const float*)d_in[6];
    const float* conv_b = (const float*)d_in[7];
    const float* bn_g   = (const float*)d_in[8];
    const float* bn_b   = (const float*)d_in[9];
    const float* bn_m   = (const float*)d_in[10];
    const float* bn_v   = (const float*)d_in[11];
    const float* ta_w1  = (const float*)d_in[12];
    const float* ta_b1  = (const float*)d_in[13];
    const float* ta_w2  = (const float*)d_in[14];
    const float* ta_b2  = (const float*)d_in[15];
    const float* fa_w1  = (const float*)d_in[16];
    const float* fa_b1  = (const float*)d_in[17];
    const float* fa_w2  = (const float*)d_in[18];
    const float* fa_b2  = (const float*)d_in[19];
    const float* ow1    = (const float*)d_in[20];
    const float* ob1    = (const float*)d_in[21];
    const float* ow2    = (const float*)d_in[22];
    const float* ob2    = (const float*)d_in[23];

    int n = in_sizes[0] / (T_ * CIN_);
    int e = in_sizes[1] / 2;
    const int* srcv = ei;
    const int* dstv = ei + e;

    char* p = (char*)d_ws;
    auto take = [&](size_t bytes) -> void* {
        void* r = (void*)p;
        p += (bytes + 255) & ~(size_t)255;
        return r;
    };
    int*   cursor    = (int*)take((size_t)n * 4);
    float* dinv      = (float*)take((size_t)n * 4);
    int*   csr_src   = (int*)take((size_t)n * SLOTS * 4);
    int2*  pack      = (int2*)take((size_t)n * SLOTS * 8);
    float* bkp       = (float*)take((size_t)3 * 3 * 64 * 4);
    unsigned short* wkA  = (unsigned short*)take((size_t)3 * 24 * 64 * 8 * 2);
    unsigned short* xabf = (unsigned short*)take((size_t)n * F_ * 2);
    unsigned short* xbbf = (unsigned short*)take((size_t)n * F_ * 2);
    unsigned short* aggb = (unsigned short*)take((size_t)n * F_ * 2);

    int nb_n = (n + 255) / 256;
    int nb_e = (e + 255) / 256;
    int nb8  = (n + 7) / 8;
    int nbG  = 8 * ((n + 3) / 4);
    int nT   = n * T_;
    int nbM  = (nT + 15) / 16;

    k_init<<<nb_n, 256, 0, stream>>>(cursor, n);
    k_fused<<<36 + nb_e + nbM, 256, 0, stream>>>(
        gcn_W, gcn_b, conv_w, wkA, bkp,
        srcv, dstv, cursor, csr_src, e,
        x, We, be, xabf, nT, nb_e, n);
    k_post<<<(n * SLOTS + 255) / 256, 256, 0, stream>>>(
        cursor, csr_src, pack, dinv, n);

    // layer 0
    k_gather<<<nbG, 256, 0, stream>>>(xabf, aggb, cursor, pack, dinv, n);
    k_conv<<<nb8, 256, 0, stream>>>(aggb, xabf, xbbf, wkA, bkp, conv_b,
                                    bn_g, bn_b, bn_m, bn_v, n);
    // layer 1
    k_gather<<<nbG, 256, 0, stream>>>(xbbf, aggb, cursor, pack, dinv, n);
    k_conv<<<nb8, 256, 0, stream>>>(aggb, xbbf, xabf,
                                    wkA + (size_t)1 * 24 * 64 * 8,
                                    bkp + (size_t)1 * 3 * 64,
                                    conv_b + (size_t)1 * H_,
                                    bn_g + (size_t)1 * H_, bn_b + (size_t)1 * H_,
                                    bn_m + (size_t)1 * H_, bn_v + (size_t)1 * H_,
                                    n);
    // layer 2 + attention
    k_gather<<<nbG, 256, 0, stream>>>(xabf, aggb, cursor, pack, dinv, n);
    k_conv_attn<<<nb8, 256, 0, stream>>>(aggb, xabf,
                                         wkA + (size_t)2 * 24 * 64 * 8,
                                         bkp + (size_t)2 * 3 * 64,
                                         conv_b + (size_t)2 * H_,
                                         bn_g + (size_t)2 * H_, bn_b + (size_t)2 * H_,
                                         bn_m + (size_t)2 * H_, bn_v + (size_t)2 * H_,
                                         ta_w1, ta_b1, ta_w2, ta_b2,
                                         fa_w1, fa_b1, fa_w2, fa_b2,
                                         ow1, ob1, ow2, ob2, (float*)d_out, n);
}

// Round 8
// 515.516 us; speedup vs baseline: 1.0150x; 1.0150x over previous
//
#include <hip/hip_runtime.h>
#include <cstddef>
#include <cstdint>

#define T_ 12
#define H_ 64
#define CIN_ 16
#define F_ 768          // H*T
#define BN_EPS 1e-5f
#define RPITCH 88       // sxb row pitch in ushorts (16B-aligned)
#define SLOTS 64        // fixed-stride CSR slots per node

// Plane-major feature layout for intermediates (xabf/xbbf/agg):
// 8 planes; plane s holds flat channels [96s, 96s+96) of every node:
// ushort index = (s*n + node)*96 + (flat%96). Flat semantics unchanged.

typedef float v2f __attribute__((ext_vector_type(2)));
typedef short s8v __attribute__((ext_vector_type(8)));
typedef float f4v __attribute__((ext_vector_type(4)));

__device__ __forceinline__ unsigned short f2bf(float f) {
    unsigned u = __float_as_uint(f);
    unsigned r = (u + 0x7FFFu + ((u >> 16) & 1u)) >> 16;
    return (unsigned short)r;
}
__device__ __forceinline__ float bf2f(unsigned short h) {
    return __uint_as_float(((unsigned)h) << 16);
}
__device__ __forceinline__ v2f bf2x2(unsigned u) {
    v2f r;
    r.x = __uint_as_float(u << 16);
    r.y = __uint_as_float(u & 0xFFFF0000u);
    return r;
}
__device__ __forceinline__ v2f pkfma(v2f a, v2f b, v2f c) {
    return __builtin_elementwise_fma(a, b, c);
}

// ---------------- slot-CSR build ----------------

__global__ void k_init(int* __restrict__ cursor, int n) {
    int i = blockIdx.x * 256 + threadIdx.x;
    if (i < n) cursor[i] = 0;
}

// ---------------- fused: wprep(+wkA pack) | scatter | embed ----------------

__global__ __launch_bounds__(256) void k_fused(
        const float* __restrict__ gcn_W, const float* __restrict__ gcn_b,
        const float* __restrict__ conv_w,
        unsigned short* __restrict__ wkA, float* __restrict__ bkp,
        const int* __restrict__ srcv, const int* __restrict__ dstv,
        int* __restrict__ cursor, int* __restrict__ csr_src, int e,
        const float* __restrict__ x, const float* __restrict__ We,
        const float* __restrict__ be, unsigned short* __restrict__ xbf, int nT,
        int nbE, int n) {
    __shared__ float smem[5312];
    int b = blockIdx.x;
    int tid = threadIdx.x;

    if (b < 36) {
        // ---- wprep: wk[l,k][c][o] = sum_d gcn_W[l][c][d] * conv_w[l][o][d][k]
        int l = b / 12, k = (b / 4) % 3, cq = b & 3;
        const float* Wg = gcn_W + (size_t)l * 4096;
        const float* cw = conv_w + (size_t)l * 12288;
        float* scwT = smem;            // [64][66]
        float* sWg  = smem + 4224;     // [16][64]
        float* sgb  = smem + 5248;     // [64]
        for (int i = tid; i < 4096; i += 256)
            scwT[(i & 63) * 66 + (i >> 6)] = cw[(size_t)i * 3 + k];
        for (int i = tid; i < 1024; i += 256)
            sWg[i] = Wg[cq * 16 * 64 + i];
        if (tid < 64) sgb[tid] = gcn_b[(size_t)l * 64 + tid];
        __syncthreads();
#pragma unroll
        for (int j = 0; j < 4; j++) {
            int idx = j * 256 + tid;
            int cc = idx >> 6;
            int o  = idx & 63;
            float acc = 0.f;
            for (int d = 0; d < 64; d++)
                acc += sWg[cc * 64 + d] * scwT[d * 66 + o];
            int cful = cq * 16 + cc;
            int kidx = k * 64 + cful;
            int ks = kidx >> 5, r = kidx & 31;
            int ln = (r >> 3) * 16 + (o & 15);
            int jj = r & 7;
            wkA[((((size_t)l * 24) + (o >> 4) * 6 + ks) * 64 + ln) * 8 + jj] =
                f2bf(acc);
        }
        if (cq == 0 && tid < 64) {
            int o = tid;
            float acc = 0.f;
            for (int d = 0; d < 64; d++)
                acc += sgb[d] * scwT[d * 66 + o];
            bkp[((size_t)l * 3 + k) * 64 + o] = acc;
        }
        return;
    }
    if (b < 36 + nbE) {
        int i = (b - 36) * 256 + tid;
        if (i < e) {
            int d = dstv[i], s = srcv[i];
            int pos = atomicAdd(&cursor[d], 1);
            if (pos < SLOTS) csr_src[d * SLOTS + pos] = s;
        }
        return;
    }
    // ---- embed (plane-major output) ----
    float* sW = smem;
    float* sb = smem + 1024;
    for (int i = tid; i < CIN_ * H_; i += 256) sW[i] = We[i];
    if (tid < H_) sb[tid] = be[tid];
    __syncthreads();
    int h4  = tid & 15;
    int ntl = tid >> 4;
    int nt  = (b - 36 - nbE) * 16 + ntl;
    if (nt >= nT) return;
    const float4* xp = (const float4*)(x + (size_t)nt * CIN_);
    float4 xv4[4];
    xv4[0] = xp[0]; xv4[1] = xp[1]; xv4[2] = xp[2]; xv4[3] = xp[3];
    const float* xs = (const float*)xv4;
    float acc[4];
#pragma unroll
    for (int j = 0; j < 4; j++) acc[j] = sb[h4 * 4 + j];
#pragma unroll
    for (int c = 0; c < CIN_; c++) {
        float4 w = *(const float4*)&sW[c * H_ + h4 * 4];
        float xc = xs[c];
        acc[0] += xc * w.x; acc[1] += xc * w.y;
        acc[2] += xc * w.z; acc[3] += xc * w.w;
    }
    ushort4 h;
    h.x = f2bf(fmaxf(acc[0], 0.f)); h.y = f2bf(fmaxf(acc[1], 0.f));
    h.z = f2bf(fmaxf(acc[2], 0.f)); h.w = f2bf(fmaxf(acc[3], 0.f));
    int node = nt / 12, tt = nt - node * 12;
    int flat = tt * 64 + h4 * 4;
    int s = flat / 96, rem = flat - s * 96;   // 4-run never crosses plane
    *(ushort4*)&xbf[((size_t)s * n + node) * 96 + rem] = h;
}

// ---------------- post: pack(src*48 uint-units, coef) + dinv ----------------

__global__ __launch_bounds__(256) void k_post(
        const int* __restrict__ cursor, const int* __restrict__ csr_src,
        int2* __restrict__ pack, float* __restrict__ dinv, int n) {
    int i = blockIdx.x * 256 + threadIdx.x;
    int node = i >> 6, slot = i & 63;
    if (node >= n) return;
    int deg = cursor[node];
    float dn = rsqrtf((float)(deg + 1));
    if (slot == 0) dinv[node] = dn;
    if (slot < min(deg, SLOTS)) {
        int s = csr_src[node * SLOTS + slot];
        float cf = rsqrtf((float)(cursor[s] + 1)) * dn;
        pack[node * SLOTS + slot] = make_int2(s * 48, __float_as_int(cf));
    }
}

// ---------------- XCD-sliced gather (plane-major, v3) ----------------
// block b: slice sl = b&7 -> XCD sl; 8 nodes per block, 2 per wave.
// Per-edge: ds_read_b128 (2 edges) + readfirstlane(row off) -> SGPR-base
// load with constant per-lane voffset + 2 cvt + 1 pkfma. Accumulation
// order identical to previous rounds (self, then slot-order edges).

__global__ __launch_bounds__(256, 8) void k_gather(
        const unsigned short* __restrict__ xin,
        unsigned short* __restrict__ agg,
        const int* __restrict__ degv, const int2* __restrict__ pack,
        const float* __restrict__ dinv, int n) {
    __shared__ __align__(16) int2 sed[4][2 * SLOTS];
    int b = blockIdx.x;
    int sl = b & 7;
    int g = b >> 3;
    int wave = threadIdx.x >> 6, lane = threadIdx.x & 63;
    int nodeA = g * 8 + wave * 2;
    if (nodeA >= n) return;
    int nodeB = nodeA + 1; if (nodeB >= n) nodeB = n - 1;
    int cntA = min(degv[nodeA], SLOTS);
    int cntB = min(degv[nodeB], SLOTS);
    if (lane < cntA) {
        long long v = __builtin_nontemporal_load(
            (const long long*)&pack[nodeA * SLOTS + lane]);
        sed[wave][lane] = *(int2*)&v;
    }
    if (lane < cntB) {
        long long v = __builtin_nontemporal_load(
            (const long long*)&pack[nodeB * SLOTS + lane]);
        sed[wave][SLOTS + lane] = *(int2*)&v;
    }
    const unsigned* xu = (const unsigned*)xin + (size_t)sl * (n * 48);
    unsigned* au = (unsigned*)agg + (size_t)sl * (n * 48);
    int lb = (lane < 48 ? lane : 47);
#pragma unroll
    for (int si = 0; si < 2; si++) {
        int node = si ? nodeB : nodeA;
        int cnt  = si ? cntB : cntA;
        const int2* sp = sed[wave] + si * SLOTS;
        float dn = dinv[node];
        float cs = dn * dn;
        v2f cs2 = {cs, cs};
        v2f acc = bf2x2(xu[node * 48 + lb]) * cs2;
        int e = 0;
        for (; e + 3 < cnt; e += 4) {
            int4 q0 = *(const int4*)&sp[e];        // edges e, e+1
            int4 q1 = *(const int4*)&sp[e + 2];    // edges e+2, e+3
            int r0 = __builtin_amdgcn_readfirstlane(q0.x);
            int r1 = __builtin_amdgcn_readfirstlane(q0.z);
            int r2 = __builtin_amdgcn_readfirstlane(q1.x);
            int r3 = __builtin_amdgcn_readfirstlane(q1.z);
            unsigned u0 = xu[r0 + lb];
            unsigned u1 = xu[r1 + lb];
            unsigned u2 = xu[r2 + lb];
            unsigned u3 = xu[r3 + lb];
            v2f c0 = {__int_as_float(q0.y), __int_as_float(q0.y)};
            v2f c1 = {__int_as_float(q0.w), __int_as_float(q0.w)};
            v2f c2 = {__int_as_float(q1.y), __int_as_float(q1.y)};
            v2f c3 = {__int_as_float(q1.w), __int_as_float(q1.w)};
            acc = pkfma(bf2x2(u0), c0, acc);
            acc = pkfma(bf2x2(u1), c1, acc);
            acc = pkfma(bf2x2(u2), c2, acc);
            acc = pkfma(bf2x2(u3), c3, acc);
        }
        for (; e < cnt; e++) {
            int2 p0 = sp[e];
            int r0 = __builtin_amdgcn_readfirstlane(p0.x);
            unsigned u0 = xu[r0 + lb];
            v2f c0 = {__int_as_float(p0.y), __int_as_float(p0.y)};
            acc = pkfma(bf2x2(u0), c0, acc);
        }
        if (lane < 48) {
            unsigned o = (unsigned)f2bf(acc.x) | ((unsigned)f2bf(acc.y) << 16);
            __builtin_nontemporal_store(o, &au[node * 48 + lane]);
        }
    }
}

// ---------------- conv core (stage agg -> LDS, MFMA, BN epilogue) ----------
// Staging: lane covers flat ushorts [12*lane, 12*lane+12) of its node's row,
// read from plane (lane>>3) at uint2 offset node*24 + (lane&7)*3 (nt loads
// via u64 bitcast: agg is a read-once stream).

#define CONV_CORE()                                                            \
    int tid = threadIdx.x;                                                     \
    int n0 = blockIdx.x * 8;                                                   \
    int wave = tid >> 6, lane = tid & 63;                                      \
    for (int i = tid; i < 8 * 2 * RPITCH; i += 256) {                          \
        int s = i / (2 * RPITCH);                                              \
        int r = i - s * (2 * RPITCH);                                          \
        int row = (r < RPITCH) ? 0 : 13;                                       \
        int c = (r < RPITCH) ? r : r - RPITCH;                                 \
        sxb[s * 14 * RPITCH + row * RPITCH + c] = 0;                           \
    }                                                                          \
    {                                                                          \
        const unsigned long long* ab = (const unsigned long long*)agg;         \
        int pofs = (lane >> 3) * (n * 24) + (lane & 7) * 3;                    \
        for (int si = 0; si < 2; si++) {                                       \
            int s = wave * 2 + si;                                             \
            int nn = n0 + s; if (nn >= n) nn = n - 1;                          \
            const unsigned long long* ap = ab + pofs + nn * 24;                \
            unsigned long long w0_ = __builtin_nontemporal_load(ap);           \
            unsigned long long w1_ = __builtin_nontemporal_load(ap + 1);       \
            unsigned long long w2_ = __builtin_nontemporal_load(ap + 2);       \
            uint2 u0 = *(uint2*)&w0_;                                          \
            uint2 u1 = *(uint2*)&w1_;                                          \
            uint2 u2 = *(uint2*)&w2_;                                          \
            unsigned short* wp = &sxb[s * 14 * RPITCH + RPITCH + lane];        \
            wp[0]           = (unsigned short)u0.x;                            \
            wp[RPITCH]      = (unsigned short)(u0.x >> 16);                    \
            wp[2 * RPITCH]  = (unsigned short)u0.y;                            \
            wp[3 * RPITCH]  = (unsigned short)(u0.y >> 16);                    \
            wp[4 * RPITCH]  = (unsigned short)u1.x;                            \
            wp[5 * RPITCH]  = (unsigned short)(u1.x >> 16);                    \
            wp[6 * RPITCH]  = (unsigned short)u1.y;                            \
            wp[7 * RPITCH]  = (unsigned short)(u1.y >> 16);                    \
            wp[8 * RPITCH]  = (unsigned short)u2.x;                            \
            wp[9 * RPITCH]  = (unsigned short)(u2.x >> 16);                    \
            wp[10 * RPITCH] = (unsigned short)u2.y;                            \
            wp[11 * RPITCH] = (unsigned short)(u2.y >> 16);                    \
        }                                                                      \
    }                                                                          \
    __syncthreads();                                                           \
    int mt = wave;                                                             \
    int q = lane >> 4;                                                         \
    int l15 = lane & 15;                                                       \
    s8v afr[6];                                                                \
    const s8v* Ap = (const s8v*)wkA;                                           \
    for (int ks = 0; ks < 6; ks++) afr[ks] = Ap[(mt * 6 + ks) * 64 + lane];    \
    int obase = mt * 16 + q * 4;                                               \
    float scl[4], shf[4], ball[4], bk0a[4], bk2a[4];                           \
    for (int r = 0; r < 4; r++) {                                              \
        int o = obase + r;                                                     \
        float sc = bng[o] * rsqrtf(bnv[o] + BN_EPS);                           \
        scl[r] = sc;                                                           \
        shf[r] = bnb[o] - bnm[o] * sc;                                         \
        float b0 = bkp[o], b1 = bkp[64 + o], b2 = bkp[128 + o];                \
        ball[r] = cb[o] + b0 + b1 + b2;                                        \
        bk0a[r] = b0; bk2a[r] = b2;                                            \
    }                                                                          \
    f4v accv[6];                                                               \
    for (int nt = 0; nt < 6; nt++) {                                           \
        int nidx = nt * 16 + l15;                                              \
        int s = nidx / 12, t = nidx - 12 * s;                                  \
        const s8v* bp = (const s8v*)&sxb[s * 14 * RPITCH + t * RPITCH + q * 8];\
        f4v acc = {0.f, 0.f, 0.f, 0.f};                                        \
        acc = __builtin_amdgcn_mfma_f32_16x16x32_bf16(afr[0], bp[0],  acc, 0, 0, 0); \
        acc = __builtin_amdgcn_mfma_f32_16x16x32_bf16(afr[1], bp[4],  acc, 0, 0, 0); \
        acc = __builtin_amdgcn_mfma_f32_16x16x32_bf16(afr[2], bp[11], acc, 0, 0, 0); \
        acc = __builtin_amdgcn_mfma_f32_16x16x32_bf16(afr[3], bp[15], acc, 0, 0, 0); \
        acc = __builtin_amdgcn_mfma_f32_16x16x32_bf16(afr[4], bp[22], acc, 0, 0, 0); \
        acc = __builtin_amdgcn_mfma_f32_16x16x32_bf16(afr[5], bp[26], acc, 0, 0, 0); \
        accv[nt] = acc;                                                        \
    }                                                                          \
    __syncthreads();                                                           \
    for (int nt = 0; nt < 6; nt++) {                                           \
        int nidx = nt * 16 + l15;                                              \
        int s = nidx / 12, t = nidx - 12 * s;                                  \
        unsigned short* dp = &sxb[s * F_ + t];                                 \
        for (int r = 0; r < 4; r++) {                                          \
            float bias = ball[r];                                              \
            if (t == 0)  bias -= bk0a[r];                                      \
            if (t == 11) bias -= bk2a[r];                                      \
            float v = (accv[nt][r] + bias) * scl[r] + shf[r];                  \
            dp[(obase + r) * 12] = f2bf(v);                                    \
        }                                                                      \
    }                                                                          \
    __syncthreads();

// ---------------- conv layers 0,1: + residual, writes xout (plane-major) ---

__global__ __launch_bounds__(256, 8) void k_conv(
        const unsigned short* __restrict__ agg,
        const unsigned short* __restrict__ xin,
        unsigned short* __restrict__ xout,
        const unsigned short* __restrict__ wkA,
        const float* __restrict__ bkp, const float* __restrict__ cb,
        const float* __restrict__ bng, const float* __restrict__ bnb,
        const float* __restrict__ bnm, const float* __restrict__ bnv,
        int n) {
    __shared__ __align__(16) unsigned short sxb[8 * 14 * RPITCH];
    CONV_CORE()

#pragma unroll
    for (int cidx = 0; cidx < 3; cidx++) {
        int c = cidx * 256 + tid;
        int s = c / 96, off = c - s * 96;
        int nn = n0 + s;
        if (nn >= n) continue;
        int sp = off / 12, rem = off - sp * 12;     // plane, uint4-within
        int gidx = sp * (n * 12) + nn * 12 + rem;   // uint4 units
        uint4 dv = *(const uint4*)&sxb[s * F_ + off * 8];
        uint4 rv = ((const uint4*)xin)[gidx];
        uint4 ov;
        unsigned* dvp = (unsigned*)&dv;
        unsigned* rvp = (unsigned*)&rv;
        unsigned* ovp = (unsigned*)&ov;
#pragma unroll
        for (int w = 0; w < 4; w++) {
            v2f d2 = bf2x2(dvp[w]);
            v2f r2 = bf2x2(rvp[w]);
            float lo = fmaxf(d2.x + r2.x, 0.f);
            float hi = fmaxf(d2.y + r2.y, 0.f);
            ovp[w] = (unsigned)f2bf(lo) | ((unsigned)f2bf(hi) << 16);
        }
        ((uint4*)xout)[gidx] = ov;
    }
}

// ---------------- conv layer 2 fused with dual attention + output MLP ------

__global__ __launch_bounds__(256, 7) void k_conv_attn(
        const unsigned short* __restrict__ agg,
        const unsigned short* __restrict__ xin,
        const unsigned short* __restrict__ wkA,
        const float* __restrict__ bkp, const float* __restrict__ cb,
        const float* __restrict__ bng, const float* __restrict__ bnb,
        const float* __restrict__ bnm, const float* __restrict__ bnv,
        const float* __restrict__ taw1, const float* __restrict__ tab1,
        const float* __restrict__ taw2, const float* __restrict__ tab2,
        const float* __restrict__ faw1, const float* __restrict__ fab1,
        const float* __restrict__ faw2, const float* __restrict__ fab2,
        const float* __restrict__ ow1, const float* __restrict__ ob1,
        const float* __restrict__ ow2, const float* __restrict__ ob2,
        float* __restrict__ out, int n) {
    __shared__ __align__(16) unsigned short sxb[8 * 14 * RPITCH];
    __shared__ float sft[96 + 520];    // s_tw [8][12] + s_xf [8][65]
    CONV_CORE()

    // residual + relu, write back to LDS (no global store)
#pragma unroll
    for (int cidx = 0; cidx < 3; cidx++) {
        int c = cidx * 256 + tid;
        int s = c / 96, off = c - s * 96;
        int nn = n0 + s; if (nn >= n) nn = n - 1;
        int sp = off / 12, rem = off - sp * 12;
        int gidx = sp * (n * 12) + nn * 12 + rem;
        uint4 dv = *(const uint4*)&sxb[s * F_ + off * 8];
        uint4 rv = ((const uint4*)xin)[gidx];
        unsigned* dvp = (unsigned*)&dv;
        unsigned* rvp = (unsigned*)&rv;
#pragma unroll
        for (int w = 0; w < 4; w++) {
            v2f d2 = bf2x2(dvp[w]);
            v2f r2 = bf2x2(rvp[w]);
            float lo = fmaxf(d2.x + r2.x, 0.f);
            float hi = fmaxf(d2.y + r2.y, 0.f);
            dvp[w] = (unsigned)f2bf(lo) | ((unsigned)f2bf(hi) << 16);
        }
        *(uint4*)&sxb[s * F_ + off * 8] = dv;
    }
    __syncthreads();

    float* s_tw = sft;          // [8][12]
    float* s_xf = sft + 96;     // [8][65]

    // ---- temporal-attn MLP: 32 threads/node, thread owns hidden unit m ----
    {
        int s2 = tid >> 5, m = tid & 31;
        float bm = tab1[m];
        v2f aa0 = {bm, bm}, aa1 = aa0, aa2 = aa0;
        v2f aa3 = aa0, aa4 = aa0, aa5 = aa0;
        const unsigned short* xr = &sxb[s2 * F_];
        float tb2 = tab2[0];
        for (int hh = 0; hh < 64; hh++) {
            const uint2* xp2 = (const uint2*)&xr[hh * 12];
            uint2 w0 = xp2[0], w1 = xp2[1], w2 = xp2[2];
            float wv = taw1[hh * 32 + m];
            v2f wv2 = {wv, wv};
            aa0 = pkfma(bf2x2(w0.x), wv2, aa0);
            aa1 = pkfma(bf2x2(w0.y), wv2, aa1);
            aa2 = pkfma(bf2x2(w1.x), wv2, aa2);
            aa3 = pkfma(bf2x2(w1.y), wv2, aa3);
            aa4 = pkfma(bf2x2(w2.x), wv2, aa4);
            aa5 = pkfma(bf2x2(w2.y), wv2, aa5);
        }
        float w2v = taw2[m];
        float av[12] = {aa0.x, aa0.y, aa1.x, aa1.y, aa2.x, aa2.y,
                        aa3.x, aa3.y, aa4.x, aa4.y, aa5.x, aa5.y};
#pragma unroll
        for (int t = 0; t < 12; t++) {
            float p = fmaxf(av[t], 0.f) * w2v;
            p += __shfl_xor(p, 1); p += __shfl_xor(p, 2);
            p += __shfl_xor(p, 4); p += __shfl_xor(p, 8);
            p += __shfl_xor(p, 16);
            if (m == 0) s_tw[s2 * 12 + t] = p + tb2;
        }
    }
    __syncthreads();

    // ---- softmax(tw), xt, feature attention: wave handles 2 nodes ----
    {
        float fb2 = fab2[0];
        for (int qi = 0; qi < 2; qi++) {
            int ss = wave * 2 + qi;
            float tw[12];
#pragma unroll
            for (int t = 0; t < 12; t++) tw[t] = s_tw[ss * 12 + t];
            float mx = tw[0];
#pragma unroll
            for (int t = 1; t < 12; t++) mx = fmaxf(mx, tw[t]);
            float sum = 0.f;
#pragma unroll
            for (int t = 0; t < 12; t++) { tw[t] = __expf(tw[t] - mx); sum += tw[t]; }
            float inv = 1.f / sum;
            const uint2* xp2 = (const uint2*)&sxb[ss * F_ + lane * 12];
            uint2 w0 = xp2[0], w1 = xp2[1], w2 = xp2[2];
            v2f x0 = bf2x2(w0.x), x1 = bf2x2(w0.y), x2 = bf2x2(w1.x);
            v2f x3 = bf2x2(w1.y), x4 = bf2x2(w2.x), x5 = bf2x2(w2.y);
            float xv[12] = {x0.x, x0.y, x1.x, x1.y, x2.x, x2.y,
                            x3.x, x3.y, x4.x, x4.y, x5.x, x5.y};
            float xt[12];
#pragma unroll
            for (int t = 0; t < 12; t++) xt[t] = xv[t] * tw[t] * inv;
            float lf = fb2;
#pragma unroll
            for (int mm = 0; mm < 6; mm++) {
                float v = fab1[mm];
#pragma unroll
                for (int t = 0; t < 12; t++) v += xt[t] * faw1[t * 6 + mm];
                lf += fmaxf(v, 0.f) * faw2[mm];
            }
            float m2v = lf;
#pragma unroll
            for (int off = 32; off >= 1; off >>= 1)
                m2v = fmaxf(m2v, __shfl_xor(m2v, off));
            float ev = __expf(lf - m2v);
            float sev = ev;
#pragma unroll
            for (int off = 32; off >= 1; off >>= 1) sev += __shfl_xor(sev, off);
            float fwv = ev / sev;
            float xs = 0.f;
#pragma unroll
            for (int t = 0; t < 12; t++) xs += xt[t];
            s_xf[ss * 65 + lane] = fwv * xs;
        }
    }
    __syncthreads();

    // ---- output MLP: 32 threads/node ----
    {
        int s2 = tid >> 5, m = tid & 31;
        float v = ob1[m];
        const float* xfp = &s_xf[s2 * 65];
        for (int hh = 0; hh < 64; hh++) v += xfp[hh] * ow1[hh * 32 + m];
        float p = fmaxf(v, 0.f) * ow2[m];
        p += __shfl_xor(p, 1); p += __shfl_xor(p, 2);
        p += __shfl_xor(p, 4); p += __shfl_xor(p, 8);
        p += __shfl_xor(p, 16);
        if (m == 0 && n0 + s2 < n) out[n0 + s2] = p + ob2[0];
    }
}

// ---------------- launcher ----------------

extern "C" void kernel_launch(void* const* d_in, const int* in_sizes, int n_in,
                              void* d_out, int out_size, void* d_ws, size_t ws_size,
                              hipStream_t stream) {
    const float* x      = (const float*)d_in[0];
    const int*   ei     = (const int*)d_in[1];
    const float* We     = (const float*)d_in[2];
    const float* be     = (const float*)d_in[3];
    const float* gcn_W  = (const float*)d_in[4];
    const float* gcn_b  = (const float*)d_in[5];
    const float* conv_w = (const float*)d_in[6];
    const float* conv_b = (const float*)d_in[7];
    const float* bn_g   = (const float*)d_in[8];
    const float* bn_b   = (const float*)d_in[9];
    const float* bn_m   = (const float*)d_in[10];
    const float* bn_v   = (const float*)d_in[11];
    const float* ta_w1  = (const float*)d_in[12];
    const float* ta_b1  = (const float*)d_in[13];
    const float* ta_w2  = (const float*)d_in[14];
    const float* ta_b2  = (const float*)d_in[15];
    const float* fa_w1  = (const float*)d_in[16];
    const float* fa_b1  = (const float*)d_in[17];
    const float* fa_w2  = (const float*)d_in[18];
    const float* fa_b2  = (const float*)d_in[19];
    const float* ow1    = (const float*)d_in[20];
    const float* ob1    = (const float*)d_in[21];
    const float* ow2    = (const float*)d_in[22];
    const float* ob2    = (const float*)d_in[23];

    int n = in_sizes[0] / (T_ * CIN_);
    int e = in_sizes[1] / 2;
    const int* srcv = ei;
    const int* dstv = ei + e;

    char* p = (char*)d_ws;
    auto take = [&](size_t bytes) -> void* {
        void* r = (void*)p;
        p += (bytes + 255) & ~(size_t)255;
        return r;
    };
    int*   cursor    = (int*)take((size_t)n * 4);
    float* dinv      = (float*)take((size_t)n * 4);
    int*   csr_src   = (int*)take((size_t)n * SLOTS * 4);
    int2*  pack      = (int2*)take((size_t)n * SLOTS * 8);
    float* bkp       = (float*)take((size_t)3 * 3 * 64 * 4);
    unsigned short* wkA  = (unsigned short*)take((size_t)3 * 24 * 64 * 8 * 2);
    unsigned short* xabf = (unsigned short*)take((size_t)n * F_ * 2);
    unsigned short* xbbf = (unsigned short*)take((size_t)n * F_ * 2);
    unsigned short* aggb = (unsigned short*)take((size_t)n * F_ * 2);

    int nb_n = (n + 255) / 256;
    int nb_e = (e + 255) / 256;
    int nb8  = (n + 7) / 8;
    int nbG  = 8 * ((n + 7) / 8);
    int nT   = n * T_;
    int nbM  = (nT + 15) / 16;

    k_init<<<nb_n, 256, 0, stream>>>(cursor, n);
    k_fused<<<36 + nb_e + nbM, 256, 0, stream>>>(
        gcn_W, gcn_b, conv_w, wkA, bkp,
        srcv, dstv, cursor, csr_src, e,
        x, We, be, xabf, nT, nb_e, n);
    k_post<<<(n * SLOTS + 255) / 256, 256, 0, stream>>>(
        cursor, csr_src, pack, dinv, n);

    // layer 0
    k_gather<<<nbG, 256, 0, stream>>>(xabf, aggb, cursor, pack, dinv, n);
    k_conv<<<nb8, 256, 0, stream>>>(aggb, xabf, xbbf, wkA, bkp, conv_b,
                                    bn_g, bn_b, bn_m, bn_v, n);
    // layer 1
    k_gather<<<nbG, 256, 0, stream>>>(xbbf, aggb, cursor, pack, dinv, n);
    k_conv<<<nb8, 256, 0, stream>>>(aggb, xbbf, xabf,
                                    wkA + (size_t)1 * 24 * 64 * 8,
                                    bkp + (size_t)1 * 3 * 64,
                                    conv_b + (size_t)1 * H_,
                                    bn_g + (size_t)1 * H_, bn_b + (size_t)1 * H_,
                                    bn_m + (size_t)1 * H_, bn_v + (size_t)1 * H_,
                                    n);
    // layer 2 + attention
    k_gather<<<nbG, 256, 0, stream>>>(xabf, aggb, cursor, pack, dinv, n);
    k_conv_attn<<<nb8, 256, 0, stream>>>(aggb, xabf,
                                         wkA + (size_t)2 * 24 * 64 * 8,
                                         bkp + (size_t)2 * 3 * 64,
                                         conv_b + (size_t)2 * H_,
                                         bn_g + (size_t)2 * H_, bn_b + (size_t)2 * H_,
                                         bn_m + (size_t)2 * H_, bn_v + (size_t)2 * H_,
                                         ta_w1, ta_b1, ta_w2, ta_b2,
                                         fa_w1, fa_b1, fa_w2, fa_b2,
                                         ow1, ob1, ow2, ob2, (float*)d_out, n);
}

// Round 9
// 402.156 us; speedup vs baseline: 1.3012x; 1.2819x over previous
//
#include <hip/hip_runtime.h>
#include <cstddef>
#include <cstdint>

#define T_ 12
#define H_ 64
#define CIN_ 16
#define F_ 768          // H*T
#define BN_EPS 1e-5f
#define ECAP 80         // staged edges per wave (2 nodes)
#define RPITCH 88       // sxb row pitch in ushorts (16B-aligned)
#define SLOTS 64        // fixed-stride CSR slots per node

typedef float v2f __attribute__((ext_vector_type(2)));
typedef short s8v __attribute__((ext_vector_type(8)));
typedef float f4v __attribute__((ext_vector_type(4)));

__device__ __forceinline__ unsigned short f2bf(float f) {
    unsigned u = __float_as_uint(f);
    unsigned r = (u + 0x7FFFu + ((u >> 16) & 1u)) >> 16;
    return (unsigned short)r;
}
__device__ __forceinline__ float bf2f(unsigned short h) {
    return __uint_as_float(((unsigned)h) << 16);
}
__device__ __forceinline__ v2f bf2x2(unsigned u) {
    v2f r;
    r.x = __uint_as_float(u << 16);
    r.y = __uint_as_float(u & 0xFFFF0000u);
    return r;
}
__device__ __forceinline__ v2f pkfma(v2f a, v2f b, v2f c) {
    return __builtin_elementwise_fma(a, b, c);
}

// ---------------- slot-CSR build ----------------

__global__ void k_init(int* __restrict__ cursor, int n) {
    int i = blockIdx.x * 256 + threadIdx.x;
    if (i < n) cursor[i] = 0;
}

// ---------------- fused: wprep(+wkA pack) | scatter | embed ----------------
// blocks [0,36): wprep -> writes wkA (bf16 fragment layout) + bkp;
// [36,36+nbE): slot scatter; rest: embed.

__global__ __launch_bounds__(256) void k_fused(
        const float* __restrict__ gcn_W, const float* __restrict__ gcn_b,
        const float* __restrict__ conv_w,
        unsigned short* __restrict__ wkA, float* __restrict__ bkp,
        const int* __restrict__ srcv, const int* __restrict__ dstv,
        int* __restrict__ cursor, int* __restrict__ csr_src, int e,
        const float* __restrict__ x, const float* __restrict__ We,
        const float* __restrict__ be, unsigned short* __restrict__ xbf, int nT,
        int nbE) {
    // aliased LDS: wprep uses scwT[64*66]+sWg[16*64]+sgb[64] = 5312 floats;
    // embed uses sW[1024]+sb[64].
    __shared__ float smem[5312];
    int b = blockIdx.x;
    int tid = threadIdx.x;

    if (b < 36) {
        // ---- wprep: wk[l,k][c][o] = sum_d gcn_W[l][c][d] * conv_w[l][o][d][k]
        // staged in LDS, written directly in wkA fragment layout (bf16).
        int l = b / 12, k = (b / 4) % 3, cq = b & 3;
        const float* Wg = gcn_W + (size_t)l * 4096;
        const float* cw = conv_w + (size_t)l * 12288;
        float* scwT = smem;            // [64][66]  scwT[d][o] = cw[(o*64+d)*3+k]
        float* sWg  = smem + 4224;     // [16][64]  rows c = cq*16 ..
        float* sgb  = smem + 5248;     // [64]
        for (int i = tid; i < 4096; i += 256)
            scwT[(i & 63) * 66 + (i >> 6)] = cw[(size_t)i * 3 + k];
        for (int i = tid; i < 1024; i += 256)
            sWg[i] = Wg[cq * 16 * 64 + i];
        if (tid < 64) sgb[tid] = gcn_b[(size_t)l * 64 + tid];
        __syncthreads();
#pragma unroll
        for (int j = 0; j < 4; j++) {
            int idx = j * 256 + tid;
            int cc = idx >> 6;         // 0..15
            int o  = idx & 63;
            float acc = 0.f;
            for (int d = 0; d < 64; d++)
                acc += sWg[cc * 64 + d] * scwT[d * 66 + o];
            // direct pack into wkA fragment layout (same value as old
            // wkp->k_post path: f2bf(acc), same summation order)
            int cful = cq * 16 + cc;
            int kidx = k * 64 + cful;           // 0..191
            int ks = kidx >> 5, r = kidx & 31;
            int ln = (r >> 3) * 16 + (o & 15);
            int jj = r & 7;
            wkA[((((size_t)l * 24) + (o >> 4) * 6 + ks) * 64 + ln) * 8 + jj] =
                f2bf(acc);
        }
        if (cq == 0 && tid < 64) {
            int o = tid;
            float acc = 0.f;
            for (int d = 0; d < 64; d++)
                acc += sgb[d] * scwT[d * 66 + o];
            bkp[((size_t)l * 3 + k) * 64 + o] = acc;
        }
        return;
    }
    if (b < 36 + nbE) {
        // ---- scatter into fixed-stride slots ----
        int i = (b - 36) * 256 + tid;
        if (i < e) {
            int d = dstv[i], s = srcv[i];
            int pos = atomicAdd(&cursor[d], 1);
            if (pos < SLOTS) csr_src[d * SLOTS + pos] = s;
        }
        return;
    }
    // ---- embed ----
    float* sW = smem;
    float* sb = smem + 1024;
    for (int i = tid; i < CIN_ * H_; i += 256) sW[i] = We[i];
    if (tid < H_) sb[tid] = be[tid];
    __syncthreads();
    int h4  = tid & 15;
    int ntl = tid >> 4;
    int nt  = (b - 36 - nbE) * 16 + ntl;
    if (nt >= nT) return;
    const float4* xp = (const float4*)(x + (size_t)nt * CIN_);
    float4 xv4[4];
    xv4[0] = xp[0]; xv4[1] = xp[1]; xv4[2] = xp[2]; xv4[3] = xp[3];
    const float* xs = (const float*)xv4;
    float acc[4];
#pragma unroll
    for (int j = 0; j < 4; j++) acc[j] = sb[h4 * 4 + j];
#pragma unroll
    for (int c = 0; c < CIN_; c++) {
        float4 w = *(const float4*)&sW[c * H_ + h4 * 4];
        float xc = xs[c];
        acc[0] += xc * w.x; acc[1] += xc * w.y;
        acc[2] += xc * w.z; acc[3] += xc * w.w;
    }
    ushort4 h;
    h.x = f2bf(fmaxf(acc[0], 0.f)); h.y = f2bf(fmaxf(acc[1], 0.f));
    h.z = f2bf(fmaxf(acc[2], 0.f)); h.w = f2bf(fmaxf(acc[3], 0.f));
    *(ushort4*)&xbf[(size_t)nt * H_ + h4 * 4] = h;
}

// ---------------- post: coef + dinv ----------------

__global__ __launch_bounds__(256) void k_post(
        const int* __restrict__ cursor, const int* __restrict__ csr_src,
        float* __restrict__ csr_coef, float* __restrict__ dinv, int n) {
    int i = blockIdx.x * 256 + threadIdx.x;
    int node = i >> 6, slot = i & 63;
    if (node >= n) return;
    int deg = cursor[node];
    float dn = rsqrtf((float)(deg + 1));
    if (slot == 0) dinv[node] = dn;
    if (slot < min(deg, SLOTS)) {
        int s = csr_src[node * SLOTS + slot];
        csr_coef[node * SLOTS + slot] = rsqrtf((float)(cursor[s] + 1)) * dn;
    }
}

// ---------------- shared layer body (macro) ----------------
// round-0 structure; se stores (row offset = src*F_, coef bits) so the hot
// loop's addressing is a 32-bit add instead of a 64-bit mul.

#define BPK(aL, aH, c2, u) { \
    aL = pkfma(bf2x2((u).x), c2, aL); \
    aH = pkfma(bf2x2((u).y), c2, aH); }

#define LAYER_GATHER_CONV()                                                    \
    int tid = threadIdx.x;                                                     \
    int n0 = blockIdx.x * 8;                                                   \
    int wave = tid >> 6, lane = tid & 63;                                      \
    int wbase = wave * (ECAP * 2);                                             \
    for (int i = tid; i < 8 * 2 * RPITCH; i += 256) {                          \
        int s = i / (2 * RPITCH);                                              \
        int r = i - s * (2 * RPITCH);                                          \
        int row = (r < RPITCH) ? 0 : 13;                                       \
        int c = (r < RPITCH) ? r : r - RPITCH;                                 \
        sxb[s * 14 * RPITCH + row * RPITCH + c] = 0;                           \
    }                                                                          \
    int begs[2], cnts[2], stgs[2], epos[2];                                    \
    {                                                                          \
        int pos = 0;                                                           \
        for (int si = 0; si < 2; si++) {                                       \
            int nn = n0 + wave * 2 + si; if (nn >= n) nn = n - 1;              \
            int beg = nn * SLOTS;                                              \
            int cnt = min(degv[nn], SLOTS);                                    \
            int stg = min(cnt, ECAP - pos);                                    \
            for (int i = lane; i < stg; i += 64) {                             \
                se[wbase + (pos + i) * 2]     = csr_src[beg + i] * F_;         \
                se[wbase + (pos + i) * 2 + 1] = __float_as_int(csr_coef[beg + i]); \
            }                                                                  \
            begs[si] = beg; cnts[si] = cnt; stgs[si] = stg; epos[si] = pos;    \
            pos += stg;                                                        \
        }                                                                      \
    }                                                                          \
    {                                                                          \
        int i0 = 3 * lane;                                                     \
        for (int si = 0; si < 2; si++) {                                       \
            int s = wave * 2 + si;                                             \
            int nn = n0 + s; if (nn >= n) nn = n - 1;                          \
            float dn = dinv[nn];                                               \
            float cs = dn * dn;                                                \
            v2f cs2 = {cs, cs};                                                \
            const uint2* xp = (const uint2*)(xin + (size_t)nn * F_);           \
            uint2 u0 = xp[i0], u1 = xp[i0 + 1], u2 = xp[i0 + 2];               \
            v2f a0 = bf2x2(u0.x) * cs2, a1 = bf2x2(u0.y) * cs2;                \
            v2f a2 = bf2x2(u1.x) * cs2, a3 = bf2x2(u1.y) * cs2;                \
            v2f a4 = bf2x2(u2.x) * cs2, a5 = bf2x2(u2.y) * cs2;                \
            int cnt = stgs[si];                                                \
            int base = wbase + epos[si] * 2;                                   \
            int e = 0;                                                         \
            for (; e + 3 < cnt; e += 4) {                                      \
                int2 p0 = *(const int2*)&se[base + e * 2];                     \
                int2 p1 = *(const int2*)&se[base + e * 2 + 2];                 \
                int2 p2 = *(const int2*)&se[base + e * 2 + 4];                 \
                int2 p3 = *(const int2*)&se[base + e * 2 + 6];                 \
                const uint2* pA = (const uint2*)(xin + p0.x);                  \
                const uint2* pB = (const uint2*)(xin + p1.x);                  \
                const uint2* pC = (const uint2*)(xin + p2.x);                  \
                const uint2* pD = (const uint2*)(xin + p3.x);                  \
                uint2 uA0 = pA[i0], uA1 = pA[i0 + 1], uA2 = pA[i0 + 2];        \
                uint2 uB0 = pB[i0], uB1 = pB[i0 + 1], uB2 = pB[i0 + 2];        \
                uint2 uC0 = pC[i0], uC1 = pC[i0 + 1], uC2 = pC[i0 + 2];        \
                uint2 uD0 = pD[i0], uD1 = pD[i0 + 1], uD2 = pD[i0 + 2];        \
                float cA = __int_as_float(p0.y), cB = __int_as_float(p1.y);    \
                float cC = __int_as_float(p2.y), cD = __int_as_float(p3.y);    \
                v2f cA2 = {cA, cA}, cB2 = {cB, cB};                            \
                v2f cC2 = {cC, cC}, cD2 = {cD, cD};                            \
                BPK(a0, a1, cA2, uA0) BPK(a2, a3, cA2, uA1) BPK(a4, a5, cA2, uA2) \
                BPK(a0, a1, cB2, uB0) BPK(a2, a3, cB2, uB1) BPK(a4, a5, cB2, uB2) \
                BPK(a0, a1, cC2, uC0) BPK(a2, a3, cC2, uC1) BPK(a4, a5, cC2, uC2) \
                BPK(a0, a1, cD2, uD0) BPK(a2, a3, cD2, uD1) BPK(a4, a5, cD2, uD2) \
            }                                                                  \
            for (; e < cnt; e++) {                                             \
                int2 p0 = *(const int2*)&se[base + e * 2];                     \
                const uint2* pA = (const uint2*)(xin + p0.x);                  \
                uint2 uA0 = pA[i0], uA1 = pA[i0 + 1], uA2 = pA[i0 + 2];        \
                float cA = __int_as_float(p0.y);                               \
                v2f cA2 = {cA, cA};                                            \
                BPK(a0, a1, cA2, uA0) BPK(a2, a3, cA2, uA1) BPK(a4, a5, cA2, uA2) \
            }                                                                  \
            for (int g = begs[si] + stgs[si]; g < begs[si] + cnts[si]; g++) {  \
                int srcO = csr_src[g] * F_;                                    \
                float cf = csr_coef[g];                                        \
                const uint2* pA = (const uint2*)(xin + srcO);                  \
                uint2 uA0 = pA[i0], uA1 = pA[i0 + 1], uA2 = pA[i0 + 2];        \
                v2f cf2 = {cf, cf};                                            \
                BPK(a0, a1, cf2, uA0) BPK(a2, a3, cf2, uA1) BPK(a4, a5, cf2, uA2) \
            }                                                                  \
            unsigned short* wp = &sxb[s * 14 * RPITCH + RPITCH + lane];        \
            float vals[12] = {a0.x, a0.y, a1.x, a1.y, a2.x, a2.y,              \
                              a3.x, a3.y, a4.x, a4.y, a5.x, a5.y};             \
            for (int t = 0; t < 12; t++) wp[t * RPITCH] = f2bf(vals[t]);       \
        }                                                                      \
    }                                                                          \
    __syncthreads();                                                           \
    int mt = wave;                                                             \
    int q = lane >> 4;                                                         \
    int l15 = lane & 15;                                                       \
    s8v afr[6];                                                                \
    const s8v* Ap = (const s8v*)wkA;                                           \
    for (int ks = 0; ks < 6; ks++) afr[ks] = Ap[(mt * 6 + ks) * 64 + lane];    \
    int obase = mt * 16 + q * 4;                                               \
    float scl[4], shf[4], ball[4], bk0a[4], bk2a[4];                           \
    for (int r = 0; r < 4; r++) {                                              \
        int o = obase + r;                                                     \
        float sc = bng[o] * rsqrtf(bnv[o] + BN_EPS);                           \
        scl[r] = sc;                                                           \
        shf[r] = bnb[o] - bnm[o] * sc;                                         \
        float b0 = bkp[o], b1 = bkp[64 + o], b2 = bkp[128 + o];                \
        ball[r] = cb[o] + b0 + b1 + b2;                                        \
        bk0a[r] = b0; bk2a[r] = b2;                                            \
    }                                                                          \
    f4v accv[6];                                                               \
    for (int nt = 0; nt < 6; nt++) {                                           \
        int nidx = nt * 16 + l15;                                              \
        int s = nidx / 12, t = nidx - 12 * s;                                  \
        const s8v* bp = (const s8v*)&sxb[s * 14 * RPITCH + t * RPITCH + q * 8];\
        f4v acc = {0.f, 0.f, 0.f, 0.f};                                        \
        acc = __builtin_amdgcn_mfma_f32_16x16x32_bf16(afr[0], bp[0],  acc, 0, 0, 0); \
        acc = __builtin_amdgcn_mfma_f32_16x16x32_bf16(afr[1], bp[4],  acc, 0, 0, 0); \
        acc = __builtin_amdgcn_mfma_f32_16x16x32_bf16(afr[2], bp[11], acc, 0, 0, 0); \
        acc = __builtin_amdgcn_mfma_f32_16x16x32_bf16(afr[3], bp[15], acc, 0, 0, 0); \
        acc = __builtin_amdgcn_mfma_f32_16x16x32_bf16(afr[4], bp[22], acc, 0, 0, 0); \
        acc = __builtin_amdgcn_mfma_f32_16x16x32_bf16(afr[5], bp[26], acc, 0, 0, 0); \
        accv[nt] = acc;                                                        \
    }                                                                          \
    __syncthreads();                                                           \
    for (int nt = 0; nt < 6; nt++) {                                           \
        int nidx = nt * 16 + l15;                                              \
        int s = nidx / 12, t = nidx - 12 * s;                                  \
        unsigned short* dp = &sxb[s * F_ + t];                                 \
        for (int r = 0; r < 4; r++) {                                          \
            float bias = ball[r];                                              \
            if (t == 0)  bias -= bk0a[r];                                      \
            if (t == 11) bias -= bk2a[r];                                      \
            float v = (accv[nt][r] + bias) * scl[r] + shf[r];                  \
            dp[(obase + r) * 12] = f2bf(v);                                    \
        }                                                                      \
    }                                                                          \
    __syncthreads();

// ---------------- fused ST layer (layers 0,1): writes xout ----------------

__global__ __launch_bounds__(256, 7) void k_layer(
        const unsigned short* __restrict__ xin,
        unsigned short* __restrict__ xout,
        const int* __restrict__ degv, const int* __restrict__ csr_src,
        const float* __restrict__ csr_coef, const float* __restrict__ dinv,
        const unsigned short* __restrict__ wkA,
        const float* __restrict__ bkp, const float* __restrict__ cb,
        const float* __restrict__ bng, const float* __restrict__ bnb,
        const float* __restrict__ bnm, const float* __restrict__ bnv,
        int n) {
    __shared__ __align__(16) unsigned short sxb[8 * 14 * RPITCH];
    __shared__ int se[4 * ECAP * 2];
    LAYER_GATHER_CONV()

#pragma unroll
    for (int cidx = 0; cidx < 3; cidx++) {
        int c = cidx * 256 + tid;
        int s = c / 96, off = c - s * 96;
        int nn = n0 + s;
        if (nn >= n) continue;
        uint4 dv = *(const uint4*)&sxb[s * F_ + off * 8];
        uint4 rv = ((const uint4*)(xin + (size_t)nn * F_))[off];
        uint4 ov;
        unsigned* dvp = (unsigned*)&dv;
        unsigned* rvp = (unsigned*)&rv;
        unsigned* ovp = (unsigned*)&ov;
#pragma unroll
        for (int w = 0; w < 4; w++) {
            v2f d2 = bf2x2(dvp[w]);
            v2f r2 = bf2x2(rvp[w]);
            float lo = fmaxf(d2.x + r2.x, 0.f);
            float hi = fmaxf(d2.y + r2.y, 0.f);
            ovp[w] = (unsigned)f2bf(lo) | ((unsigned)f2bf(hi) << 16);
        }
        *(uint4*)(xout + (size_t)nn * F_ + off * 8) = ov;
    }
}

// ---------------- last layer fused with dual attention + output MLP --------

__global__ __launch_bounds__(256, 6) void k_layer_attn(
        const unsigned short* __restrict__ xin,
        const int* __restrict__ degv, const int* __restrict__ csr_src,
        const float* __restrict__ csr_coef, const float* __restrict__ dinv,
        const unsigned short* __restrict__ wkA,
        const float* __restrict__ bkp, const float* __restrict__ cb,
        const float* __restrict__ bng, const float* __restrict__ bnb,
        const float* __restrict__ bnm, const float* __restrict__ bnv,
        const float* __restrict__ taw1, const float* __restrict__ tab1,
        const float* __restrict__ taw2, const float* __restrict__ tab2,
        const float* __restrict__ faw1, const float* __restrict__ fab1,
        const float* __restrict__ faw2, const float* __restrict__ fab2,
        const float* __restrict__ ow1, const float* __restrict__ ob1,
        const float* __restrict__ ow2, const float* __restrict__ ob2,
        float* __restrict__ out, int n) {
    __shared__ __align__(16) unsigned short sxb[8 * 14 * RPITCH];
    __shared__ int se[4 * ECAP * 2];   // reused: s_tw (96 f) + s_xf (520 f)
    LAYER_GATHER_CONV()

    // residual + relu, write back to LDS (no global store)
#pragma unroll
    for (int cidx = 0; cidx < 3; cidx++) {
        int c = cidx * 256 + tid;
        int s = c / 96, off = c - s * 96;
        int nn = n0 + s; if (nn >= n) nn = n - 1;
        uint4 dv = *(const uint4*)&sxb[s * F_ + off * 8];
        uint4 rv = ((const uint4*)(xin + (size_t)nn * F_))[off];
        unsigned* dvp = (unsigned*)&dv;
        unsigned* rvp = (unsigned*)&rv;
#pragma unroll
        for (int w = 0; w < 4; w++) {
            v2f d2 = bf2x2(dvp[w]);
            v2f r2 = bf2x2(rvp[w]);
            float lo = fmaxf(d2.x + r2.x, 0.f);
            float hi = fmaxf(d2.y + r2.y, 0.f);
            dvp[w] = (unsigned)f2bf(lo) | ((unsigned)f2bf(hi) << 16);
        }
        *(uint4*)&sxb[s * F_ + off * 8] = dv;
    }
    __syncthreads();

    float* s_tw = (float*)se;          // [8][12]
    float* s_xf = (float*)se + 96;     // [8][65]

    // ---- temporal-attn MLP: 32 threads/node, thread owns hidden unit m ----
    {
        int s2 = tid >> 5, m = tid & 31;
        float bm = tab1[m];
        v2f aa0 = {bm, bm}, aa1 = aa0, aa2 = aa0;
        v2f aa3 = aa0, aa4 = aa0, aa5 = aa0;
        const unsigned short* xr = &sxb[s2 * F_];
        float tb2 = tab2[0];
        for (int hh = 0; hh < 64; hh++) {
            const uint2* xp2 = (const uint2*)&xr[hh * 12];
            uint2 w0 = xp2[0], w1 = xp2[1], w2 = xp2[2];
            float wv = taw1[hh * 32 + m];
            v2f wv2 = {wv, wv};
            aa0 = pkfma(bf2x2(w0.x), wv2, aa0);
            aa1 = pkfma(bf2x2(w0.y), wv2, aa1);
            aa2 = pkfma(bf2x2(w1.x), wv2, aa2);
            aa3 = pkfma(bf2x2(w1.y), wv2, aa3);
            aa4 = pkfma(bf2x2(w2.x), wv2, aa4);
            aa5 = pkfma(bf2x2(w2.y), wv2, aa5);
        }
        float w2v = taw2[m];
        float av[12] = {aa0.x, aa0.y, aa1.x, aa1.y, aa2.x, aa2.y,
                        aa3.x, aa3.y, aa4.x, aa4.y, aa5.x, aa5.y};
#pragma unroll
        for (int t = 0; t < 12; t++) {
            float p = fmaxf(av[t], 0.f) * w2v;
            p += __shfl_xor(p, 1); p += __shfl_xor(p, 2);
            p += __shfl_xor(p, 4); p += __shfl_xor(p, 8);
            p += __shfl_xor(p, 16);
            if (m == 0) s_tw[s2 * 12 + t] = p + tb2;
        }
    }
    __syncthreads();

    // ---- softmax(tw), xt, feature attention: wave handles 2 nodes ----
    {
        float fb2 = fab2[0];
        for (int qi = 0; qi < 2; qi++) {
            int ss = wave * 2 + qi;
            float tw[12];
#pragma unroll
            for (int t = 0; t < 12; t++) tw[t] = s_tw[ss * 12 + t];
            float mx = tw[0];
#pragma unroll
            for (int t = 1; t < 12; t++) mx = fmaxf(mx, tw[t]);
            float sum = 0.f;
#pragma unroll
            for (int t = 0; t < 12; t++) { tw[t] = __expf(tw[t] - mx); sum += tw[t]; }
            float inv = 1.f / sum;
            const uint2* xp2 = (const uint2*)&sxb[ss * F_ + lane * 12];
            uint2 w0 = xp2[0], w1 = xp2[1], w2 = xp2[2];
            v2f x0 = bf2x2(w0.x), x1 = bf2x2(w0.y), x2 = bf2x2(w1.x);
            v2f x3 = bf2x2(w1.y), x4 = bf2x2(w2.x), x5 = bf2x2(w2.y);
            float xv[12] = {x0.x, x0.y, x1.x, x1.y, x2.x, x2.y,
                            x3.x, x3.y, x4.x, x4.y, x5.x, x5.y};
            float xt[12];
#pragma unroll
            for (int t = 0; t < 12; t++) xt[t] = xv[t] * tw[t] * inv;
            float lf = fb2;
#pragma unroll
            for (int mm = 0; mm < 6; mm++) {
                float v = fab1[mm];
#pragma unroll
                for (int t = 0; t < 12; t++) v += xt[t] * faw1[t * 6 + mm];
                lf += fmaxf(v, 0.f) * faw2[mm];
            }
            float m2v = lf;
#pragma unroll
            for (int off = 32; off >= 1; off >>= 1)
                m2v = fmaxf(m2v, __shfl_xor(m2v, off));
            float ev = __expf(lf - m2v);
            float sev = ev;
#pragma unroll
            for (int off = 32; off >= 1; off >>= 1) sev += __shfl_xor(sev, off);
            float fwv = ev / sev;
            float xs = 0.f;
#pragma unroll
            for (int t = 0; t < 12; t++) xs += xt[t];
            s_xf[ss * 65 + lane] = fwv * xs;
        }
    }
    __syncthreads();

    // ---- output MLP: 32 threads/node ----
    {
        int s2 = tid >> 5, m = tid & 31;
        float v = ob1[m];
        const float* xfp = &s_xf[s2 * 65];
        for (int hh = 0; hh < 64; hh++) v += xfp[hh] * ow1[hh * 32 + m];
        float p = fmaxf(v, 0.f) * ow2[m];
        p += __shfl_xor(p, 1); p += __shfl_xor(p, 2);
        p += __shfl_xor(p, 4); p += __shfl_xor(p, 8);
        p += __shfl_xor(p, 16);
        if (m == 0 && n0 + s2 < n) out[n0 + s2] = p + ob2[0];
    }
}

// ---------------- launcher ----------------

extern "C" void kernel_launch(void* const* d_in, const int* in_sizes, int n_in,
                              void* d_out, int out_size, void* d_ws, size_t ws_size,
                              hipStream_t stream) {
    const float* x      = (const float*)d_in[0];
    const int*   ei     = (const int*)d_in[1];
    const float* We     = (const float*)d_in[2];
    const float* be     = (const float*)d_in[3];
    const float* gcn_W  = (const float*)d_in[4];
    const float* gcn_b  = (const float*)d_in[5];
    const float* conv_w = (const float*)d_in[6];
    const float* conv_b = (const float*)d_in[7];
    const float* bn_g   = (const float*)d_in[8];
    const float* bn_b   = (const float*)d_in[9];
    const float* bn_m   = (const float*)d_in[10];
    const float* bn_v   = (const float*)d_in[11];
    const float* ta_w1  = (const float*)d_in[12];
    const float* ta_b1  = (const float*)d_in[13];
    const float* ta_w2  = (const float*)d_in[14];
    const float* ta_b2  = (const float*)d_in[15];
    const float* fa_w1  = (const float*)d_in[16];
    const float* fa_b1  = (const float*)d_in[17];
    const float* fa_w2  = (const float*)d_in[18];
    const float* fa_b2  = (const float*)d_in[19];
    const float* ow1    = (const float*)d_in[20];
    const float* ob1    = (const float*)d_in[21];
    const float* ow2    = (const float*)d_in[22];
    const float* ob2    = (const float*)d_in[23];

    int n = in_sizes[0] / (T_ * CIN_);
    int e = in_sizes[1] / 2;
    const int* srcv = ei;
    const int* dstv = ei + e;

    char* p = (char*)d_ws;
    auto take = [&](size_t bytes) -> void* {
        void* r = (void*)p;
        p += (bytes + 255) & ~(size_t)255;
        return r;
    };
    int*   cursor    = (int*)take((size_t)n * 4);
    float* dinv      = (float*)take((size_t)n * 4);
    int*   csr_src   = (int*)take((size_t)n * SLOTS * 4);
    float* csr_coef  = (float*)take((size_t)n * SLOTS * 4);
    float* bkp       = (float*)take((size_t)3 * 3 * 64 * 4);
    unsigned short* wkA = (unsigned short*)take((size_t)3 * 24 * 64 * 8 * 2);
    unsigned short* xabf = (unsigned short*)take((size_t)n * F_ * 2);
    unsigned short* xbbf = (unsigned short*)take((size_t)n * F_ * 2);

    int nb_n = (n + 255) / 256;
    int nb_e = (e + 255) / 256;
    int nb8  = (n + 7) / 8;
    int nT   = n * T_;
    int nbM  = (nT + 15) / 16;

    k_init<<<nb_n, 256, 0, stream>>>(cursor, n);
    k_fused<<<36 + nb_e + nbM, 256, 0, stream>>>(
        gcn_W, gcn_b, conv_w, wkA, bkp,
        srcv, dstv, cursor, csr_src, e,
        x, We, be, xabf, nT, nb_e);
    k_post<<<(n * SLOTS + 255) / 256, 256, 0, stream>>>(
        cursor, csr_src, csr_coef, dinv, n);

    // layers 0,1
    k_layer<<<nb8, 256, 0, stream>>>(xabf, xbbf, cursor, csr_src, csr_coef,
                                     dinv, wkA, bkp, conv_b,
                                     bn_g, bn_b, bn_m, bn_v, n);
    k_layer<<<nb8, 256, 0, stream>>>(xbbf, xabf, cursor, csr_src, csr_coef,
                                     dinv, wkA + (size_t)1 * 24 * 64 * 8,
                                     bkp + (size_t)1 * 3 * 64,
                                     conv_b + (size_t)1 * H_,
                                     bn_g + (size_t)1 * H_, bn_b + (size_t)1 * H_,
                                     bn_m + (size_t)1 * H_, bn_v + (size_t)1 * H_,
                                     n);
    // layer 2 fused with attention
    k_layer_attn<<<nb8, 256, 0, stream>>>(xabf, cursor, csr_src, csr_coef,
                                          dinv, wkA + (size_t)2 * 24 * 64 * 8,
                                          bkp + (size_t)2 * 3 * 64,
                                          conv_b + (size_t)2 * H_,
                                          bn_g + (size_t)2 * H_, bn_b + (size_t)2 * H_,
                                          bn_m + (size_t)2 * H_, bn_v + (size_t)2 * H_,
                                          ta_w1, ta_b1, ta_w2, ta_b2,
                                          fa_w1, fa_b1, fa_w2, fa_b2,
                                          ow1, ob1, ow2, ob2, (float*)d_out, n);
}